// Round 5
// baseline (64.944 us; speedup 1.0000x reference)
//
#include <hip/hip_runtime.h>

// 7x7 stride-2 VALID cross-correlation, X: 4096x4096 fp32, out: 2045x2045 fp32.
// out[i,j] = sum_{p,q} X[2i+p, 2j+q] * W[p,q]
//
// Tile: 32 output rows x 64 cols. Grid 1024 blocks x 2 tiles each
// (horizontally adjacent), software-pipelined: while computing tile k from
// LDS, tile k+1's global loads are in flight into registers (T14/2-phase).
// LDS 40 KiB single buffer, XOR-swizzled addresses, all reg indices static.

static constexpr int H     = 4096;
static constexpr int OUT   = 2045;  // (4096-7)/2 + 1
static constexpr int P4    = 36;    // float4 slots per LDS row (XOR-safe pad)
static constexpr int NIT   = 10;    // ceil(69*36 / 256) staging iterations
static constexpr int SLOTS = 2560;  // NIT * 256

__device__ __forceinline__ void issue_loads(const float* __restrict__ X,
                                            int C0, int R0, int t,
                                            float4 (&st)[NIT])
{
#pragma unroll
    for (int it = 0; it < NIT; ++it) {
        const int l     = t + 256 * it;
        const int lrow  = l / P4;
        const int col4  = l - lrow * P4;
        const int s     = (lrow >> 2) & 3;
        const int chunk = col4 ^ s;           // slot u holds logical chunk u^s
        int grow = R0 + lrow;       if (grow > H - 1) grow = H - 1;  // garbage only
        int gcol = C0 + 4 * chunk;  if (gcol > H - 4) gcol = H - 4;  // guarded outputs
        st[it] = *reinterpret_cast<const float4*>(X + (size_t)grow * H + gcol);
    }
}

__global__ __launch_bounds__(256, 4) void conv7s2_kernel(
    const float* __restrict__ X,
    const float* __restrict__ W,
    float* __restrict__ out)
{
    __shared__ float4 lds4[SLOTS];   // 40 KiB -> 4 blocks/CU

    const int t = threadIdx.x;
    const int b = blockIdx.x;

    // Uniform-address weight loads -> SGPRs.
    float w[49];
#pragma unroll
    for (int i = 0; i < 49; ++i) w[i] = W[i];

    const int tx = t & 15;    // 16 threads x 4 output cols
    const int ty = t >> 4;    // 16 threads x 2 output rows
    const int c2 = 2 * tx;    // first logical chunk this lane needs

    // Prologue: issue tile 0 loads.
    float4 st[NIT];
    {
        const int tid = 2 * b;
        issue_loads(X, (tid & 31) * 128, (tid >> 5) * 64, t, st);
    }

#pragma unroll
    for (int k = 0; k < 2; ++k) {
        const int tid = 2 * b + k;
        const int bx  = tid & 31;
        const int by  = tid >> 5;

        __syncthreads();                       // prev compute done reading LDS
#pragma unroll
        for (int it = 0; it < NIT; ++it)       // vmcnt auto-inserted before write
            lds4[t + 256 * it] = st[it];       // lane-linear: conflict-free
        __syncthreads();

        if (k == 0) {                          // prefetch tile 1 UNDER the compute
            const int tid1 = 2 * b + 1;
            issue_loads(X, (tid1 & 31) * 128, (tid1 >> 5) * 64, t, st);
        }

        float acc0[4] = {0.f, 0.f, 0.f, 0.f};
        float acc1[4] = {0.f, 0.f, 0.f, 0.f};

#pragma unroll
        for (int r = 0; r < 9; ++r) {
            const int lrow    = 4 * ty + r;
            const int rowbase = lrow * P4;
            const int s       = (lrow >> 2) & 3;

            float rv[16];                      // static indices only
#pragma unroll
            for (int i = 0; i < 4; ++i) {
                const float4 v = lds4[rowbase + ((c2 + i) ^ s)];
                rv[4 * i + 0] = v.x;
                rv[4 * i + 1] = v.y;
                rv[4 * i + 2] = v.z;
                rv[4 * i + 3] = v.w;
            }

#pragma unroll
            for (int q = 0; q < 7; ++q) {
#pragma unroll
                for (int j = 0; j < 4; ++j) {
                    const float cv = rv[2 * j + q];
                    if (r <= 6) acc0[j] = fmaf(cv, w[r * 7 + q],       acc0[j]);
                    if (r >= 2) acc1[j] = fmaf(cv, w[(r - 2) * 7 + q], acc1[j]);
                }
            }
        }

        const int x0 = bx * 64 + tx * 4;
        const int y0 = by * 32 + ty * 2;
#pragma unroll
        for (int j = 0; j < 4; ++j) {
            const int x = x0 + j;
            if (x < OUT) {
                if (y0     < OUT) out[(size_t)y0       * OUT + x] = acc0[j];
                if (y0 + 1 < OUT) out[(size_t)(y0 + 1) * OUT + x] = acc1[j];
            }
        }
    }
}

extern "C" void kernel_launch(void* const* d_in, const int* in_sizes, int n_in,
                              void* d_out, int out_size, void* d_ws, size_t ws_size,
                              hipStream_t stream) {
    const float* X = (const float*)d_in[0];
    const float* W = (const float*)d_in[1];
    float* out = (float*)d_out;

    conv7s2_kernel<<<dim3(1024), 256, 0, stream>>>(X, W, out);
}

// Round 6
// 48.591 us; speedup vs baseline: 1.3365x; 1.3365x over previous
//
#include <hip/hip_runtime.h>

// 7x7 stride-2 VALID cross-correlation, X: 4096x4096 fp32, out: 2045x2045 fp32.
// out[i,j] = sum_{p,q} X[2i+p, 2j+q] * W[p,q]
//
// Tile: 32 output rows x 64 cols; grid 512 blocks x 4 horizontally-adjacent
// tiles, 2-phase register-prefetch pipeline (issue tile k+1 loads before
// computing tile k). LDS 44 KiB single buffer, XOR-swizzle set {0,1,4,5}
// with ty-minor lanes: every 8 consecutive lanes cover all 8 bank quads.
// All register indices compile-time (no scratch); launch_bounds(256,2).

static constexpr int H     = 4096;
static constexpr int OUT   = 2045;   // (4096-7)/2 + 1
static constexpr int P4    = 40;     // float4 slots per LDS row (XOR-safe, in-row)
static constexpr int NIT   = 11;     // ceil(69*40 / 256)
static constexpr int SLOTS = NIT * 256;   // 2816 float4 = 44 KiB

__device__ __forceinline__ int sel_swz(int q) {   // q in 0..3 -> {0,1,4,5}
    return (q & 1) | ((q & 2) << 1);
}

__global__ __launch_bounds__(256, 2) void conv7s2_kernel(
    const float* __restrict__ X,
    const float* __restrict__ W,
    float* __restrict__ out)
{
    __shared__ float4 lds4[SLOTS];

    const int t = threadIdx.x;
    const int b = blockIdx.x;

    // Uniform-address weight loads -> SGPRs.
    float w[49];
#pragma unroll
    for (int i = 0; i < 49; ++i) w[i] = W[i];

    // ty-minor lane mapping: lanes 0..3 = 4 row-groups, bits 2..5 = col-group.
    const int tysub = t & 3;
    const int c     = (t >> 2) & 15;   // col-group: output cols 4c..4c+3
    const int wv    = t >> 6;
    const int rg    = tysub + 4 * wv;  // row-group: output rows 2rg, 2rg+1

    // Tile-independent staging decomposition: slot l = t + 256*it ->
    // (lrow, u); slot holds global chunk u ^ s(lrow).
    int lrowA[NIT], G4A[NIT];
#pragma unroll
    for (int it = 0; it < NIT; ++it) {
        const int l  = t + 256 * it;
        const int lr = l / P4;
        const int u  = l - lr * P4;
        lrowA[it] = lr;
        G4A[it]   = 4 * (u ^ sel_swz((lr >> 2) & 3));
    }

    // Prologue: issue tile 0 loads.
    float4 st[NIT];
    {
        const int tid = 4 * b;
        const int C0  = (tid & 31) * 128;
        const int R0  = (tid >> 5) * 64;
#pragma unroll
        for (int it = 0; it < NIT; ++it) {
            int grow = R0 + lrowA[it];  if (grow > H - 1) grow = H - 1;  // garbage only
            int gcol = C0 + G4A[it];    if (gcol > H - 4) gcol = H - 4;  // guarded outputs
            st[it] = *reinterpret_cast<const float4*>(X + (size_t)grow * H + gcol);
        }
    }

    const int c2 = 2 * c;
    const int s0 = sel_swz(rg & 3);          // r = 0..3
    const int s1 = sel_swz((rg + 1) & 3);    // r = 4..7
    const int s2 = sel_swz((rg + 2) & 3);    // r = 8

#pragma unroll 1
    for (int k = 0; k < 4; ++k) {
        const int tid = 4 * b + k;
        const int bx  = tid & 31;
        const int by  = tid >> 5;

        __syncthreads();                       // prev compute done reading LDS
#pragma unroll
        for (int it = 0; it < NIT; ++it)       // vmcnt drain auto-inserted
            lds4[t + 256 * it] = st[it];       // lane-linear: 8-quad coverage
        __syncthreads();

        if (k < 3) {                           // prefetch next tile UNDER compute
            const int tid1 = tid + 1;
            const int C0   = (tid1 & 31) * 128;
            const int R0   = (tid1 >> 5) * 64;
#pragma unroll
            for (int it = 0; it < NIT; ++it) {
                int grow = R0 + lrowA[it];  if (grow > H - 1) grow = H - 1;
                int gcol = C0 + G4A[it];    if (gcol > H - 4) gcol = H - 4;
                st[it] = *reinterpret_cast<const float4*>(X + (size_t)grow * H + gcol);
            }
        }

        float acc0[4] = {0.f, 0.f, 0.f, 0.f};
        float acc1[4] = {0.f, 0.f, 0.f, 0.f};

#pragma unroll
        for (int r = 0; r < 9; ++r) {
            const int lrow = 4 * rg + r;
            const int base = lrow * P4;
            const int s    = (r < 4) ? s0 : (r < 8) ? s1 : s2;  // static per r

            float rv[16];                      // static indices only
#pragma unroll
            for (int i = 0; i < 4; ++i) {
                const float4 v = lds4[base + ((c2 + i) ^ s)];
                rv[4 * i + 0] = v.x;
                rv[4 * i + 1] = v.y;
                rv[4 * i + 2] = v.z;
                rv[4 * i + 3] = v.w;
            }

#pragma unroll
            for (int q = 0; q < 7; ++q) {
#pragma unroll
                for (int j = 0; j < 4; ++j) {
                    const float cv = rv[2 * j + q];
                    if (r <= 6) acc0[j] = fmaf(cv, w[r * 7 + q],       acc0[j]);
                    if (r >= 2) acc1[j] = fmaf(cv, w[(r - 2) * 7 + q], acc1[j]);
                }
            }
        }

        const int x0 = bx * 64 + 4 * c;
        const int y0 = by * 32 + 2 * rg;
#pragma unroll
        for (int j = 0; j < 4; ++j) {
            const int x = x0 + j;
            if (x < OUT) {
                if (y0     < OUT) out[(size_t)y0       * OUT + x] = acc0[j];
                if (y0 + 1 < OUT) out[(size_t)(y0 + 1) * OUT + x] = acc1[j];
            }
        }
    }
}

extern "C" void kernel_launch(void* const* d_in, const int* in_sizes, int n_in,
                              void* d_out, int out_size, void* d_ws, size_t ws_size,
                              hipStream_t stream) {
    const float* X = (const float*)d_in[0];
    const float* W = (const float*)d_in[1];
    float* out = (float*)d_out;

    conv7s2_kernel<<<dim3(512), 256, 0, stream>>>(X, W, out);   // 512 x 4 tiles = 2048
}

// Round 7
// 23.709 us; speedup vs baseline: 2.7392x; 2.0494x over previous
//
#include <hip/hip_runtime.h>
#include <stdint.h>

// 7x7 stride-2 VALID cross-correlation, X: 4096x4096 fp32, out: 2045x2045 fp32.
// out[i,j] = sum_{p,q} X[2i+p, 2j+q] * W[p,q]
//
// Tile: 32 output rows x 64 cols; grid 512 blocks x 4 horizontally-adjacent
// tiles. Staging is global_load_lds DMA (zero data VGPRs -> nothing to spill),
// double-buffered LDS (2 x 39.7 KB -> 2 blocks/CU). 2-phase pipeline:
// issue next-tile DMA, compute current tile, one vmcnt-drain+barrier per tile
// (the drain lands after the ~1500-cycle compute, so DMA overlaps compute).
// XOR swizzle lives in the per-lane GLOBAL address; LDS layout is lane-linear
// (required by global_load_lds: wave-uniform base + lane*16).

static constexpr int H     = 4096;
static constexpr int OUT   = 2045;           // (4096-7)/2 + 1
static constexpr int P4    = 36;             // float4 slots per LDS row
static constexpr int ROWS  = 69;             // input rows per tile footprint
static constexpr int SLOTS = ROWS * P4;      // 2484 float4 = 39744 B
static constexpr int NIT   = (SLOTS + 255) / 256;   // 10 (last iter partial)
static constexpr int NT    = 4;              // tiles per block

__global__ __launch_bounds__(256) void conv7s2_kernel(
    const float* __restrict__ X,
    const float* __restrict__ W,
    float* __restrict__ out)
{
    __shared__ float4 lds4[2][SLOTS];        // 79488 B -> 2 blocks/CU

    const int t = threadIdx.x;
    const int b = blockIdx.x;

    // Uniform-address weight loads -> SGPRs.
    float w[49];
#pragma unroll
    for (int i = 0; i < 49; ++i) w[i] = W[i];

    // Tile-independent staging decomposition: slot l = t + 256*it ->
    // (lrow, u); slot u of row lrow holds global chunk u ^ s(lrow),
    // s(lrow) = (lrow>>2)&3  (XOR-closed within P4=36: s subset bits 0..1).
    int lrowA[NIT], chA[NIT];
#pragma unroll
    for (int it = 0; it < NIT; ++it) {
        const int l  = t + 256 * it;
        const int lr = l / P4;
        const int u  = l - lr * P4;
        lrowA[it] = lr;
        chA[it]   = u ^ ((lr >> 2) & 3);
    }

    // ty-minor lane mapping.
    const int tysub = t & 3;
    const int c     = (t >> 2) & 15;   // col-group: output cols 4c..4c+3
    const int wv    = t >> 6;
    const int rg    = tysub + 4 * wv;  // row-group: output rows 2rg, 2rg+1
    const int c2    = 2 * c;

    auto stage = [&](int buf, int tid) {
        const int C0 = (tid & 31) * 128;
        const int R0 = (tid >> 5) * 64;
#pragma unroll
        for (int it = 0; it < NIT; ++it) {
            const int l = t + 256 * it;
            if (l < SLOTS) {   // active lanes form a prefix of each wave
                int grow = R0 + lrowA[it];     if (grow > H - 1) grow = H - 1; // garbage only
                int gcol = C0 + 4 * chA[it];   if (gcol > H - 4) gcol = H - 4; // guarded outputs
                const float* gp = X + (size_t)grow * H + gcol;
                __builtin_amdgcn_global_load_lds(
                    (const __attribute__((address_space(1))) uint32_t*)gp,
                    (__attribute__((address_space(3))) uint32_t*)&lds4[buf][l],
                    16, 0, 0);
            }
        }
    };

    // Prologue: tile 0 into buffer 0.
    stage(0, 4 * b);
    __syncthreads();                    // vmcnt drain + join

#pragma unroll
    for (int k = 0; k < NT; ++k) {
        const int cur = k & 1;          // static after unroll
        const int tid = 4 * b + k;
        const int bx  = tid & 31;
        const int by  = tid >> 5;

        // Issue next tile's DMA BEFORE compute; it lands during the FMAs.
        if (k + 1 < NT) stage(cur ^ 1, tid + 1);

        float acc0[4] = {0.f, 0.f, 0.f, 0.f};
        float acc1[4] = {0.f, 0.f, 0.f, 0.f};

#pragma unroll
        for (int r = 0; r < 9; ++r) {
            const int lrow = 4 * rg + r;
            const int base = lrow * P4;
            const int s    = (rg + (r >> 2)) & 3;   // static per r

            float rv[16];               // static register indices only
#pragma unroll
            for (int i = 0; i < 4; ++i) {
                const float4 v = lds4[cur][base + ((c2 + i) ^ s)];
                rv[4 * i + 0] = v.x;
                rv[4 * i + 1] = v.y;
                rv[4 * i + 2] = v.z;
                rv[4 * i + 3] = v.w;
            }

#pragma unroll
            for (int q = 0; q < 7; ++q) {
#pragma unroll
                for (int j = 0; j < 4; ++j) {
                    const float cv = rv[2 * j + q];
                    if (r <= 6) acc0[j] = fmaf(cv, w[r * 7 + q],       acc0[j]);
                    if (r >= 2) acc1[j] = fmaf(cv, w[(r - 2) * 7 + q], acc1[j]);
                }
            }
        }

        const int x0 = bx * 64 + 4 * c;
        const int y0 = by * 32 + 2 * rg;
#pragma unroll
        for (int j = 0; j < 4; ++j) {
            const int x = x0 + j;
            if (x < OUT) {
                if (y0     < OUT) out[(size_t)y0       * OUT + x] = acc0[j];
                if (y0 + 1 < OUT) out[(size_t)(y0 + 1) * OUT + x] = acc1[j];
            }
        }

        // One drain+barrier per tile: next tile's DMA has had the whole
        // compute phase to land; also fences buffer reuse.
        if (k + 1 < NT) __syncthreads();
    }
}

extern "C" void kernel_launch(void* const* d_in, const int* in_sizes, int n_in,
                              void* d_out, int out_size, void* d_ws, size_t ws_size,
                              hipStream_t stream) {
    const float* X = (const float*)d_in[0];
    const float* W = (const float*)d_in[1];
    float* out = (float*)d_out;

    conv7s2_kernel<<<dim3(512), 256, 0, stream>>>(X, W, out);   // 512 x 4 = 2048 tiles
}